// Round 1
// baseline (592.952 us; speedup 1.0000x reference)
//
#include <hip/hip_runtime.h>
#include <math.h>

namespace {
constexpr int B   = 4;
constexpr int CIN = 128;   // high channels
constexpr int CO  = 64;    // up / aligned channels
constexpr int HF  = 64;    // high H=W
constexpr int HO  = 128;   // up/out H=W
constexpr int HW  = HO * HO;   // 16384
constexpr int NOFF = 27;   // 18 offset + 9 mask channels

// workspace layout (float offsets)
constexpr size_t UPT   = 0;                          // [B][HO][HO][CO]  NHWC up
constexpr size_t FOO   = UPT  + (size_t)B * HW * CO; // [B][27][HO][HO]  offsets+mask
constexpr size_t WTUP  = FOO  + (size_t)B * NOFF * HW; // [3][3][CIN][CO]
constexpr size_t WTOFF = WTUP + (size_t)9 * CIN * CO;  // [CIN][9][32]
constexpr size_t WTAL  = WTOFF + (size_t)CIN * 9 * 32; // [9][CO][CO]
}

// ---------------- weight repack: put output channel innermost (uniform s_load) ----
__global__ void k_repack(const float* __restrict__ wup, const float* __restrict__ woff,
                         const float* __restrict__ wal, float* __restrict__ ws) {
  int i = blockIdx.x * 256 + threadIdx.x;
  if (i < 9 * CIN * CO) {                 // src w_up[c][o][ry][rx] -> [ry][rx][c][o]
    int rx = i % 3; int t = i / 3; int ry = t % 3; t /= 3;
    int o = t % CO; int c = t / CO;
    ws[WTUP + ((size_t)(ry * 3 + rx) * CIN + c) * CO + o] = wup[i];
  }
  if (i < CIN * 9 * 32) {                 // dst [c][kt][32] from w_off[oc][c][ky][kx]
    int oc = i & 31; int t = i >> 5; int kt = t % 9; int c = t / 9;
    float v = 0.f;
    if (oc < NOFF) v = woff[((size_t)(oc * CIN + c) * 3 + kt / 3) * 3 + (kt % 3)];
    ws[WTOFF + i] = v;
  }
  if (i < 9 * CO * CO) {                  // dst [k][c][o] from w_align[o][c][k]
    int o = i & 63; int t = i >> 6; int c = t & 63; int k = t >> 6;
    ws[WTAL + i] = wal[((size_t)o * CO + c) * 9 + k];
  }
}

// ---------------- K1: transposed conv (parity-decomposed), NHWC output -----------
// grid (16 tiles, 4 parity, B*2 o-halves), block 256 = 16x16 same-parity pixels
__global__ __launch_bounds__(256) void k_up(const float* __restrict__ high,
                                            const float* __restrict__ bup,
                                            float* __restrict__ ws) {
  __shared__ float lds[4][17][17];
  const float* wt = ws + WTUP;
  float* upT = ws + UPT;

  const int t  = threadIdx.x;
  const int p  = blockIdx.y; const int py = p >> 1, px = p & 1;
  const int b  = blockIdx.z >> 1; const int oh = (blockIdx.z & 1) * 32;
  const int tY = (blockIdx.x >> 2) * 32, tX = (blockIdx.x & 3) * 32;
  const int sy = t >> 4, sx = t & 15;
  const int iyB = tY >> 1, ixB = tX >> 1;

  float acc[32];
#pragma unroll
  for (int j = 0; j < 32; j++) acc[j] = 0.f;

  // tap tables (uniform per block except the LDS row/col which is per-thread)
  int relY[2], ryA[2], nty, relX[2], rxA[2], ntx;
  if (py == 0) { nty = 1; relY[0] = sy;     ryA[0] = 1; relY[1] = 0;      ryA[1] = 0; }
  else         { nty = 2; relY[0] = sy;     ryA[0] = 2; relY[1] = sy + 1; ryA[1] = 0; }
  if (px == 0) { ntx = 1; relX[0] = sx;     rxA[0] = 1; relX[1] = 0;      rxA[1] = 0; }
  else         { ntx = 2; relX[0] = sx;     rxA[0] = 2; relX[1] = sx + 1; rxA[1] = 0; }

  for (int c0 = 0; c0 < CIN; c0 += 4) {
    __syncthreads();
    for (int i = t; i < 4 * 289; i += 256) {
      int cl = i / 289; int rem = i - cl * 289; int r = rem / 17; int cc = rem - r * 17;
      int iy = iyB + r, ix = ixB + cc;
      float v = 0.f;
      if (iy < HF && ix < HF) v = high[((size_t)(b * CIN + c0 + cl) * HF + iy) * HF + ix];
      lds[cl][r][cc] = v;
    }
    __syncthreads();
#pragma unroll
    for (int cl = 0; cl < 4; cl++) {
      int c = c0 + cl;
#pragma unroll
      for (int ti = 0; ti < 2; ti++) {
        if (ti < nty) {
#pragma unroll
          for (int tj = 0; tj < 2; tj++) {
            if (tj < ntx) {
              float v = lds[cl][relY[ti]][relX[tj]];
              const float4* w4 =
                  (const float4*)(wt + ((size_t)(ryA[ti] * 3 + rxA[tj]) * CIN + c) * CO + oh);
#pragma unroll
              for (int j = 0; j < 8; j++) {
                float4 w = w4[j];
                acc[4 * j + 0] = fmaf(v, w.x, acc[4 * j + 0]);
                acc[4 * j + 1] = fmaf(v, w.y, acc[4 * j + 1]);
                acc[4 * j + 2] = fmaf(v, w.z, acc[4 * j + 2]);
                acc[4 * j + 3] = fmaf(v, w.w, acc[4 * j + 3]);
              }
            }
          }
        }
      }
    }
  }

  const int y = tY + 2 * sy + py, x = tX + 2 * sx + px;
  float* dst = upT + (((size_t)b * HO + y) * HO + x) * CO + oh;
#pragma unroll
  for (int j = 0; j < 8; j++) {
    float4 o4;
    o4.x = acc[4 * j + 0] + bup[oh + 4 * j + 0];
    o4.y = acc[4 * j + 1] + bup[oh + 4 * j + 1];
    o4.z = acc[4 * j + 2] + bup[oh + 4 * j + 2];
    o4.w = acc[4 * j + 3] + bup[oh + 4 * j + 3];
    ((float4*)dst)[j] = o4;
  }
}

// ---------------- K2: 3x3 conv over concat(up NHWC, low NCHW) -> offsets+mask ----
// grid (8 xtiles, 16 ytiles, B), block 128 = 8x16 pixels
__global__ __launch_bounds__(128) void k_off(const float* __restrict__ low,
                                             const float* __restrict__ boff,
                                             float* __restrict__ ws) {
  __shared__ float lds[8][10][18];
  const float* upT = ws + UPT;
  const float* wt  = ws + WTOFF;
  float* fo = ws + FOO;

  const int t  = threadIdx.x;
  const int b  = blockIdx.z;
  const int tY = blockIdx.y * 8, tX = blockIdx.x * 16;
  const int sy = t >> 4, sx = t & 15;
  const int y = tY + sy, x = tX + sx;

  float acc[28];
#pragma unroll
  for (int j = 0; j < 28; j++) acc[j] = 0.f;

  for (int c0 = 0; c0 < CIN; c0 += 8) {
    __syncthreads();
    if (c0 < CO) {  // channels from up (NHWC): 8 contiguous floats per pixel
      for (int i = t; i < 180; i += 128) {
        int r = i / 18, cc = i - 18 * r;
        int gy = tY - 1 + r, gx = tX - 1 + cc;
        float4 a = {0, 0, 0, 0}, b4 = {0, 0, 0, 0};
        if (gy >= 0 && gy < HO && gx >= 0 && gx < HO) {
          const float4* ptr = (const float4*)(upT + (((size_t)b * HO + gy) * HO + gx) * CO + c0);
          a = ptr[0]; b4 = ptr[1];
        }
        lds[0][r][cc] = a.x;  lds[1][r][cc] = a.y;  lds[2][r][cc] = a.z;  lds[3][r][cc] = a.w;
        lds[4][r][cc] = b4.x; lds[5][r][cc] = b4.y; lds[6][r][cc] = b4.z; lds[7][r][cc] = b4.w;
      }
    } else {        // channels from low (NCHW planes)
      for (int i = t; i < 8 * 180; i += 128) {
        int cl = i / 180; int rem = i - 180 * cl; int r = rem / 18; int cc = rem - 18 * r;
        int gy = tY - 1 + r, gx = tX - 1 + cc;
        float v = 0.f;
        if (gy >= 0 && gy < HO && gx >= 0 && gx < HO)
          v = low[((size_t)(b * CO + (c0 - CO + cl)) * HO + gy) * HO + gx];
        lds[cl][r][cc] = v;
      }
    }
    __syncthreads();
#pragma unroll 2
    for (int cl = 0; cl < 8; cl++) {
      int c = c0 + cl;
#pragma unroll
      for (int ky = 0; ky < 3; ky++)
#pragma unroll
        for (int kx = 0; kx < 3; kx++) {
          float v = lds[cl][sy + ky][sx + kx];
          const float4* w4 = (const float4*)(wt + ((size_t)c * 9 + ky * 3 + kx) * 32);
#pragma unroll
          for (int j = 0; j < 7; j++) {
            float4 w = w4[j];
            acc[4 * j + 0] = fmaf(v, w.x, acc[4 * j + 0]);
            acc[4 * j + 1] = fmaf(v, w.y, acc[4 * j + 1]);
            acc[4 * j + 2] = fmaf(v, w.z, acc[4 * j + 2]);
            acc[4 * j + 3] = fmaf(v, w.w, acc[4 * j + 3]);
          }
        }
    }
  }

#pragma unroll
  for (int oc = 0; oc < NOFF; oc++) {
    float v = acc[oc] + boff[oc];
    if (oc >= 18) v = 2.f / (1.f + expf(-v));   // mask = 2*sigmoid
    fo[(((size_t)b * NOFF + oc) * HO + y) * HO + x] = v;
  }
}

// ---------------- K3: modulated deformable conv + leaky relu ---------------------
// grid (64 tiles, B), block 256 = 16x16 pixels; gathers float4 channels from NHWC up
__global__ __launch_bounds__(256) void k_dcn(const float* __restrict__ bal,
                                             float* __restrict__ out,
                                             const float* __restrict__ ws) {
  const float* upT = ws + UPT;
  const float* fo  = ws + FOO;
  const float* wt  = ws + WTAL;

  const int t  = threadIdx.x;
  const int b  = blockIdx.y;
  const int tY = (blockIdx.x >> 3) * 16, tX = (blockIdx.x & 7) * 16;
  const int sy = t >> 4, sx = t & 15;
  const int y = tY + sy, x = tX + sx;

  float4 acc4[16];
#pragma unroll
  for (int j = 0; j < 16; j++) acc4[j] = make_float4(0.f, 0.f, 0.f, 0.f);

  const float* foB = fo + (size_t)b * NOFF * HW + y * HO + x;
  const float* upB = upT + (size_t)b * HW * CO;

#pragma unroll 1
  for (int k = 0; k < 9; k++) {
    int ky = k / 3, kx = k % 3;
    float offy = foB[(size_t)(2 * k) * HW];
    float offx = foB[(size_t)(2 * k + 1) * HW];
    float m    = foB[(size_t)(18 + k) * HW];
    float pyf = offy + (float)(y - 1 + ky);
    float pxf = offx + (float)(x - 1 + kx);
    float y0f = floorf(pyf), x0f = floorf(pxf);
    float wy = pyf - y0f, wx = pxf - x0f;
    int y0 = (int)y0f, x0 = (int)x0f;
    int y1 = y0 + 1, x1 = x0 + 1;
    float vy0 = (y0 >= 0 && y0 < HO) ? 1.f : 0.f;
    float vy1 = (y1 >= 0 && y1 < HO) ? 1.f : 0.f;
    float vx0 = (x0 >= 0 && x0 < HO) ? 1.f : 0.f;
    float vx1 = (x1 >= 0 && x1 < HO) ? 1.f : 0.f;
    float w00 = (1.f - wy) * (1.f - wx) * vy0 * vx0 * m;
    float w01 = (1.f - wy) * wx         * vy0 * vx1 * m;
    float w10 = wy         * (1.f - wx) * vy1 * vx0 * m;
    float w11 = wy         * wx         * vy1 * vx1 * m;
    int cy0 = min(max(y0, 0), HO - 1), cy1 = min(max(y1, 0), HO - 1);
    int cx0 = min(max(x0, 0), HO - 1), cx1 = min(max(x1, 0), HO - 1);
    const float4* p00 = (const float4*)(upB + ((size_t)cy0 * HO + cx0) * CO);
    const float4* p01 = (const float4*)(upB + ((size_t)cy0 * HO + cx1) * CO);
    const float4* p10 = (const float4*)(upB + ((size_t)cy1 * HO + cx0) * CO);
    const float4* p11 = (const float4*)(upB + ((size_t)cy1 * HO + cx1) * CO);
    const float* wk = wt + (size_t)k * CO * CO;

#pragma unroll 2
    for (int c4 = 0; c4 < 16; c4++) {
      float4 a00 = p00[c4], a01 = p01[c4], a10 = p10[c4], a11 = p11[c4];
      float vv[4];
      vv[0] = fmaf(w00, a00.x, fmaf(w01, a01.x, fmaf(w10, a10.x, w11 * a11.x)));
      vv[1] = fmaf(w00, a00.y, fmaf(w01, a01.y, fmaf(w10, a10.y, w11 * a11.y)));
      vv[2] = fmaf(w00, a00.z, fmaf(w01, a01.z, fmaf(w10, a10.z, w11 * a11.z)));
      vv[3] = fmaf(w00, a00.w, fmaf(w01, a01.w, fmaf(w10, a10.w, w11 * a11.w)));
#pragma unroll
      for (int cc = 0; cc < 4; cc++) {
        float vc = vv[cc];
        const float4* w4 = (const float4*)(wk + (size_t)(c4 * 4 + cc) * CO);
#pragma unroll
        for (int j = 0; j < 16; j++) {
          float4 w = w4[j];
          acc4[j].x = fmaf(vc, w.x, acc4[j].x);
          acc4[j].y = fmaf(vc, w.y, acc4[j].y);
          acc4[j].z = fmaf(vc, w.z, acc4[j].z);
          acc4[j].w = fmaf(vc, w.w, acc4[j].w);
        }
      }
    }
  }

  float* ob = out + (size_t)b * 2 * CO * HW + y * HO + x;
#pragma unroll
  for (int j = 0; j < 16; j++) {
    float vals[4] = {acc4[j].x, acc4[j].y, acc4[j].z, acc4[j].w};
#pragma unroll
    for (int cc = 0; cc < 4; cc++) {
      int o = 4 * j + cc;
      float v = vals[cc] + bal[o];
      v = (v >= 0.f) ? v : 0.2f * v;          // leaky relu
      ob[(size_t)o * HW] = v;
    }
  }
}

// ---------------- K4: copy low_feature into out channels 64..127 -----------------
__global__ void k_copy(const float* __restrict__ low, float* __restrict__ out) {
  int i = blockIdx.x * 256 + threadIdx.x;       // over B*CO*HW/4 float4s
  int b = i >> 18;                              // 262144 float4 per batch
  float4 v = ((const float4*)low)[i];
  ((float4*)out)[i + (b + 1) * 262144] = v;
}

extern "C" void kernel_launch(void* const* d_in, const int* in_sizes, int n_in,
                              void* d_out, int out_size, void* d_ws, size_t ws_size,
                              hipStream_t stream) {
  const float* high = (const float*)d_in[0];
  const float* low  = (const float*)d_in[1];
  const float* wup  = (const float*)d_in[2];
  const float* bup  = (const float*)d_in[3];
  const float* woff = (const float*)d_in[4];
  const float* boff = (const float*)d_in[5];
  const float* wal  = (const float*)d_in[6];
  const float* bal  = (const float*)d_in[7];
  float* out = (float*)d_out;
  float* ws  = (float*)d_ws;

  k_repack<<<dim3(288), dim3(256), 0, stream>>>(wup, woff, wal, ws);
  k_up<<<dim3(16, 4, B * 2), dim3(256), 0, stream>>>(high, bup, ws);
  k_off<<<dim3(8, 16, B), dim3(128), 0, stream>>>(low, boff, ws);
  k_dcn<<<dim3(64, B), dim3(256), 0, stream>>>(bal, out, ws);
  k_copy<<<dim3(4096), dim3(256), 0, stream>>>(low, out);
}